// Round 12
// baseline (47.075 us; speedup 1.0000x reference)
//
#include <hip/hip_runtime.h>
#include <hip/hip_bf16.h>

// TimeAwareFullAttention: O = softmax(SCALE * decay(b,l) * Q K^T) V
// B=8 H=8 L=S=1024 E=64, f32 in/out. decay = exp(-td/5), SCALE = 1/sqrt(5).
// Round 12 = round 10 (last PASS) + ONE in-iteration reordering: V fragments
// are ds_read into REGISTERS immediately after the QK MFMAs issue (they
// depend only on the staged tile, not on s), so the 8 ds_read_b128 overlap
// the exp2/cvt/permlane VALU block; PV consumes registers. No carried
// state across iterations (rounds 9/11 showed cross-iteration MFMA-operand
// lifetimes around the inline-asm permlane miscompile -> avoided).
// Structure: 512-thr blocks, 2x 4-wave KV-split halves, each K/V dbuf
// (64 KB LDS), 32x32x16 MFMA, in-reg P via cvt_pk+permlane32_swap, fixed-m
// softmax with raw v_exp_f32, XCD swizzle, swizzled bf16 K/V workspace.

#define Lq   1024
#define Sk   1024
#define Ed   64
#define QBLK 128
#define KVBLK 64
#define NTH  8             // kv tiles per half-group
#define NBH  64            // B*H

typedef __attribute__((ext_vector_type(8)))  short          short8;
typedef __attribute__((ext_vector_type(8)))  unsigned short ushort8;
typedef __attribute__((ext_vector_type(4)))  float          f32x4;
typedef __attribute__((ext_vector_type(16))) float          f32x16;
typedef __attribute__((ext_vector_type(4)))  unsigned int   uint4v;

__device__ __forceinline__ unsigned short f2bf(float x) {
    unsigned int u = __float_as_uint(x);
    u += 0x7FFFu + ((u >> 16) & 1u);   // round-to-nearest-even
    return (unsigned short)(u >> 16);
}

__device__ __forceinline__ unsigned cvt_pk_bf16(float lo, float hi) {
    unsigned r;
    asm("v_cvt_pk_bf16_f32 %0, %1, %2" : "=v"(r) : "v"(lo), "v"(hi));
    return r;
}

__device__ __forceinline__ void gl_lds16(const void* g, void* lds) {
    __builtin_amdgcn_global_load_lds(
        (const __attribute__((address_space(1))) void*)g,
        (__attribute__((address_space(3))) void*)lds, 16, 0, 0);
}

// ---- fused pre-pass ----
// K: bf16, 16B-block swizzled: Kb[row][ (jb ^ (row&7))*8 + i ] = K[row][jb*8+i]
// V: bf16 transposed per (b,h), swizzled within each 64-kv group:
//    Vt[bh][e][kv0 + (jb ^ (e&7))*8 + i] = V[bh][kv0 + jb*8 + i][e]
__global__ __launch_bounds__(256) void prep_kv(const float* __restrict__ K,
                                               const float* __restrict__ V,
                                               unsigned short* __restrict__ Kb,
                                               unsigned short* __restrict__ Vt) {
    int bid = blockIdx.x;
    if (bid < 2048) {
        int gid = bid * 256 + threadIdx.x;   // over (B*H*S)*8
        int row = gid >> 3;
        int jb  = gid & 7;
        const float* src = K + (size_t)row * Ed + jb * 8;
        float4 a = *(const float4*)src;
        float4 c = *(const float4*)(src + 4);
        ushort8 w;
        w[0]=f2bf(a.x); w[1]=f2bf(a.y); w[2]=f2bf(a.z); w[3]=f2bf(a.w);
        w[4]=f2bf(c.x); w[5]=f2bf(c.y); w[6]=f2bf(c.z); w[7]=f2bf(c.w);
        *(ushort8*)(Kb + (size_t)row * Ed + ((jb ^ (row & 7)) << 3)) = w;
    } else {
        int vb  = bid - 2048;
        int bh  = vb >> 4;
        int kv0 = (vb & 15) * KVBLK;
        int e   = threadIdx.x & 63;
        int jh  = threadIdx.x >> 6;
        const float* Vg = V + (size_t)bh * Sk * Ed;
        unsigned short* Vo = Vt + (size_t)bh * Ed * Sk;
        #pragma unroll
        for (int half = 0; half < 2; ++half) {
            int jb = jh + half * 4;
            ushort8 w;
            #pragma unroll
            for (int i = 0; i < 8; ++i)
                w[i] = f2bf(Vg[(size_t)(kv0 + jb * 8 + i) * Ed + e]);  // coalesced over e
            *(ushort8*)(Vo + (size_t)e * Sk + kv0 + ((jb ^ (e & 7)) << 3)) = w;
        }
    }
}

// ------------------------------- main kernel --------------------------------
__global__ __launch_bounds__(512, 4) void ta_attn12(
    const float* __restrict__ Q, const float* __restrict__ TD,
    const unsigned short* __restrict__ Kb, const unsigned short* __restrict__ Vt,
    float* __restrict__ O)
{
    // [half][ K dbuf 2x8KB | V dbuf 2x8KB ] = 64 KB; reused for the combine.
    __shared__ __align__(16) char smem[65536];

    // T1: 512 wgs -> XCD d%8 owns 64 contiguous wgs = 8 (b,h) x 8 q-blocks
    const int d    = blockIdx.x;
    const int wg   = (d & 7) * 64 + (d >> 3);
    const int bh   = wg >> 3;
    const int qb   = wg & 7;
    const int b    = bh >> 3;
    const int tid  = threadIdx.x;
    const int wave = tid >> 6, lane = tid & 63;
    const int half = wave >> 2, qw = wave & 3;
    const int ln31 = lane & 31;
    const int hi   = lane >> 5;
    const int l7   = ln31 & 7;
    const int st   = tid & 255;          // staging index within the half-group

    const char* KbBH = (const char*)(Kb + (size_t)bh * Sk * Ed);
    const char* VtBH = (const char*)(Vt + (size_t)bh * Ed * Sk);
    const int q0w = qb * QBLK + qw * 32;

    char* baseK = smem + half * 32768;
    char* baseV = baseK + 16384;

    // ---- stage this half's tile 0 ----
    {
        const size_t tg = (size_t)(half * NTH);
        #pragma unroll
        for (int p = 0; p < 2; ++p) {
            unsigned o_ = st * 16 + p * 4096;
            gl_lds16(KbBH + tg * 8192 + o_, baseK + o_);
            unsigned e = o_ >> 7, c = o_ & 127;
            gl_lds16(VtBH + (size_t)e * 2048 + tg * 128 + c, baseV + o_);
        }
    }

    // ---- Q fragments (B operand): col=q=ln31, k = kc*16 + hi*8 + j ----
    const float SCALE = 0.44721359549995793f;
    const float LOG2E = 1.4426950408889634f;
    const float rscale = SCALE * LOG2E * __expf(-TD[b * Lq + q0w + ln31] * 0.2f);
    short8 qa[4];
    {
        const float* qp = Q + ((size_t)bh * Lq + q0w + ln31) * Ed + hi * 8;
        #pragma unroll
        for (int kc = 0; kc < 4; ++kc) {
            float4 a = *(const float4*)(qp + kc * 16);
            float4 c = *(const float4*)(qp + kc * 16 + 4);
            ushort8 t;
            t[0]=f2bf(a.x*rscale); t[1]=f2bf(a.y*rscale);
            t[2]=f2bf(a.z*rscale); t[3]=f2bf(a.w*rscale);
            t[4]=f2bf(c.x*rscale); t[5]=f2bf(c.y*rscale);
            t[6]=f2bf(c.z*rscale); t[7]=f2bf(c.w*rscale);
            qa[kc] = __builtin_bit_cast(short8, t);
        }
    }

    float sum = 0.f;                 // in-lane partial denominator for q=ln31
    f32x16 o[2];
    #pragma unroll
    for (int eb = 0; eb < 2; ++eb)
        #pragma unroll
        for (int i = 0; i < 16; ++i) o[eb][i] = 0.f;

    int cur = 0;
    for (int tt = 0; tt < NTH; ++tt) {
        __syncthreads();   // tile staged (vmcnt drained); prev reads done
        if (tt + 1 < NTH) {
            const size_t tg = (size_t)(half * NTH + tt + 1);
            char* kd = baseK + (cur ^ 1) * 8192;
            char* vd = baseV + (cur ^ 1) * 8192;
            #pragma unroll
            for (int p = 0; p < 2; ++p) {
                unsigned o_ = st * 16 + p * 4096;
                gl_lds16(KbBH + tg * 8192 + o_, kd + o_);
                unsigned e = o_ >> 7, c = o_ & 127;
                gl_lds16(VtBH + (size_t)e * 2048 + tg * 128 + c, vd + o_);
            }
        }
        const char* kb = baseK + cur * 8192;
        const char* vb = baseV + cur * 8192;

        // ---- S^T = K Q^T : D[kv 32 per kvb][q=ln31], A=K rows, B=Q ----
        f32x16 s[2];
        __builtin_amdgcn_s_setprio(1);
        #pragma unroll
        for (int kvb = 0; kvb < 2; ++kvb) {
            #pragma unroll
            for (int i = 0; i < 16; ++i) s[kvb][i] = 0.f;
            #pragma unroll
            for (int kc = 0; kc < 4; ++kc) {
                ushort8 kr = *(const ushort8*)(kb
                    + (kvb * 32 + ln31) * 128 + (((2 * kc + hi) ^ l7) << 4));
                s[kvb] = __builtin_amdgcn_mfma_f32_32x32x16_bf16(
                    __builtin_bit_cast(short8, kr), qa[kc], s[kvb], 0, 0, 0);
            }
        }
        __builtin_amdgcn_s_setprio(0);

        // ---- V fragments -> registers NOW (independent of s): these 8
        // ds_read_b128 overlap the exp2/cvt/permlane VALU block below ----
        ushort8 vf[2][4];
        #pragma unroll
        for (int eb = 0; eb < 2; ++eb)
            #pragma unroll
            for (int ks = 0; ks < 4; ++ks)
                vf[eb][ks] = *(const ushort8*)(vb
                    + (eb * 32 + ln31) * 128 + (((2 * ks + hi) ^ l7) << 4));

        // ---- P = 2^s via raw v_exp_f32 (scores within +-~35, no denorm
        // handling needed); in-lane sum; pack pairs w[kvb][m'][h] ----
        unsigned w[2][4][2];
        #pragma unroll
        for (int kvb = 0; kvb < 2; ++kvb)
            #pragma unroll
            for (int mp = 0; mp < 4; ++mp) {
                float p0 = __builtin_amdgcn_exp2f(s[kvb][4 * mp + 0]);
                float p1 = __builtin_amdgcn_exp2f(s[kvb][4 * mp + 1]);
                float p2 = __builtin_amdgcn_exp2f(s[kvb][4 * mp + 2]);
                float p3 = __builtin_amdgcn_exp2f(s[kvb][4 * mp + 3]);
                sum += (p0 + p1) + (p2 + p3);
                w[kvb][mp][0] = cvt_pk_bf16(p0, p1);
                w[kvb][mp][1] = cvt_pk_bf16(p2, p3);
            }

        // ---- permlane32_swap -> pa[ks] in LINEAR kv order ----
        short8 pa[4];
        #pragma unroll
        for (int ks = 0; ks < 4; ++ks) {
            const int kvb = ks >> 1, mm = ks & 1;
            unsigned a0 = w[kvb][2 * mm][0], b0 = w[kvb][2 * mm + 1][0];
            unsigned a1 = w[kvb][2 * mm][1], b1 = w[kvb][2 * mm + 1][1];
            asm volatile("v_permlane32_swap_b32 %0, %1" : "+v"(a0), "+v"(b0));
            asm volatile("v_permlane32_swap_b32 %0, %1" : "+v"(a1), "+v"(b1));
            uint4v u; u[0] = a0; u[1] = a1; u[2] = b0; u[3] = b1;
            pa[ks] = __builtin_bit_cast(short8, u);
        }

        // ---- O += P V : A=pa (row=q=ln31), B=vf (registers) ----
        __builtin_amdgcn_s_setprio(1);
        #pragma unroll
        for (int eb = 0; eb < 2; ++eb)
            #pragma unroll
            for (int ks = 0; ks < 4; ++ks)
                o[eb] = __builtin_amdgcn_mfma_f32_32x32x16_bf16(
                    pa[ks], __builtin_bit_cast(short8, vf[eb][ks]), o[eb], 0, 0, 0);
        __builtin_amdgcn_s_setprio(0);
        cur ^= 1;
    }

    // ---- combine halves through LDS (K/V buffers are dead now) ----
    __syncthreads();
    float* Lo = (float*)smem;              // 32 KB: [qw][eb*4+c4][lane] f32x4
    float* Ls = (float*)(smem + 32768);    // 1 KB:  [qw][lane]
    if (half == 1) {
        Ls[qw * 64 + lane] = sum + __shfl_xor(sum, 32);
        #pragma unroll
        for (int eb = 0; eb < 2; ++eb)
            #pragma unroll
            for (int c4 = 0; c4 < 4; ++c4) {
                f32x4 v = { o[eb][c4*4+0], o[eb][c4*4+1],
                            o[eb][c4*4+2], o[eb][c4*4+3] };
                *(f32x4*)(Lo + qw * 2048 + (eb * 4 + c4) * 256 + lane * 4) = v;
            }
    }
    __syncthreads();
    if (half == 0) {
        float stot = sum + __shfl_xor(sum, 32) + Ls[qw * 64 + lane];
        #pragma unroll
        for (int eb = 0; eb < 2; ++eb)
            #pragma unroll
            for (int c4 = 0; c4 < 4; ++c4) {
                f32x4 v = *(const f32x4*)(Lo + qw * 2048 + (eb * 4 + c4) * 256 + lane * 4);
                o[eb][c4*4+0] += v[0]; o[eb][c4*4+1] += v[1];
                o[eb][c4*4+2] += v[2]; o[eb][c4*4+3] += v[3];
            }
        float* Og = O + (size_t)bh * Lq * Ed;
        #pragma unroll
        for (int r = 0; r < 16; ++r) {
            const int qrow = (r & 3) + 8 * (r >> 2) + 4 * hi;
            float inv = 1.0f / __shfl(stot, qrow);
            float* op = Og + (size_t)(q0w + qrow) * Ed + ln31;
            op[0]  = o[0][r] * inv;
            op[32] = o[1][r] * inv;
        }
    }
}

// ------------------- round-1 fallback (ws too small) ------------------------
__global__ __launch_bounds__(256, 2) void ta_attn_fb(
    const float* __restrict__ Q, const float* __restrict__ K,
    const float* __restrict__ V, const float* __restrict__ TD,
    float* __restrict__ O)
{
    __shared__ __align__(16) unsigned short Kl[32][72];
    __shared__ __align__(16) unsigned short Vt[Ed][40];
    __shared__ __align__(16) unsigned short Pl[4][16][40];

    const int bid  = blockIdx.x;
    const int bh   = bid >> 4;
    const int qb   = bid & 15;
    const int b    = bh >> 3;
    const int tid  = threadIdx.x;
    const int wave = tid >> 6, lane = tid & 63;
    const int lg   = lane >> 4;
    const int ln   = lane & 15;

    const float* Qg = Q + (size_t)bh * Lq * Ed;
    const float* Kg = K + (size_t)bh * Sk * Ed;
    const float* Vg = V + (size_t)bh * Sk * Ed;
    const int q0 = qb * 64 + wave * 16;

    short8 qa[2];
    {
        const float* qp = Qg + (size_t)(q0 + ln) * Ed + lg * 8;
        for (int ks = 0; ks < 2; ++ks) {
            float4 a = *(const float4*)(qp + ks * 32);
            float4 c = *(const float4*)(qp + ks * 32 + 4);
            ushort8 t2;
            t2[0]=f2bf(a.x); t2[1]=f2bf(a.y); t2[2]=f2bf(a.z); t2[3]=f2bf(a.w);
            t2[4]=f2bf(c.x); t2[5]=f2bf(c.y); t2[6]=f2bf(c.z); t2[7]=f2bf(c.w);
            qa[ks] = __builtin_bit_cast(short8, t2);
        }
    }

    const float SCALE = 0.44721359549995793f;
    float rs[4], m[4], sum[4];
    for (int r = 0; r < 4; ++r) {
        int row = q0 + lg * 4 + r;
        rs[r]  = SCALE * __expf(-TD[b * Lq + row] * 0.2f);
        m[r]   = -1e30f;
        sum[r] = 0.f;
    }
    f32x4 o[4];
    for (int eb = 0; eb < 4; ++eb) o[eb] = (f32x4){0.f, 0.f, 0.f, 0.f};

    const int srow = tid >> 3;
    const int scol = (tid & 7) * 8;

    for (int t = 0; t < 32; ++t) {
        const int kv0 = t * 32;
        __syncthreads();
        {
            const float* kp = Kg + (size_t)(kv0 + srow) * Ed + scol;
            float4 a = *(const float4*)kp;
            float4 c = *(const float4*)(kp + 4);
            ushort8 tk;
            tk[0]=f2bf(a.x); tk[1]=f2bf(a.y); tk[2]=f2bf(a.z); tk[3]=f2bf(a.w);
            tk[4]=f2bf(c.x); tk[5]=f2bf(c.y); tk[6]=f2bf(c.z); tk[7]=f2bf(c.w);
            *(ushort8*)&Kl[srow][scol] = tk;
            const float* vp = Vg + (size_t)(kv0 + srow) * Ed + scol;
            float4 va = *(const float4*)vp;
            float4 vc = *(const float4*)(vp + 4);
            float vv[8] = {va.x,va.y,va.z,va.w,vc.x,vc.y,vc.z,vc.w};
            #pragma unroll
            for (int i = 0; i < 8; ++i) Vt[scol + i][srow] = f2bf(vv[i]);
        }
        __syncthreads();

        f32x4 s[2];
        #pragma unroll
        for (int cb = 0; cb < 2; ++cb) {
            s[cb] = (f32x4){0.f, 0.f, 0.f, 0.f};
            #pragma unroll
            for (int ks = 0; ks < 2; ++ks) {
                ushort8 kraw = *(const ushort8*)&Kl[cb*16 + ln][lg*8 + ks*32];
                s[cb] = __builtin_amdgcn_mfma_f32_16x16x32_bf16(
                    qa[ks], __builtin_bit_cast(short8, kraw), s[cb], 0, 0, 0);
            }
        }
        #pragma unroll
        for (int r = 0; r < 4; ++r) {
            float s0 = s[0][r] * rs[r];
            float s1 = s[1][r] * rs[r];
            float tm = fmaxf(s0, s1);
            tm = fmaxf(tm, __shfl_xor(tm, 1));
            tm = fmaxf(tm, __shfl_xor(tm, 2));
            tm = fmaxf(tm, __shfl_xor(tm, 4));
            tm = fmaxf(tm, __shfl_xor(tm, 8));
            float mn   = fmaxf(m[r], tm);
            float corr = __expf(m[r] - mn);
            m[r] = mn;
            float p0 = __expf(s0 - mn);
            float p1 = __expf(s1 - mn);
            float ts = p0 + p1;
            ts += __shfl_xor(ts, 1);
            ts += __shfl_xor(ts, 2);
            ts += __shfl_xor(ts, 4);
            ts += __shfl_xor(ts, 8);
            sum[r] = sum[r] * corr + ts;
            #pragma unroll
            for (int eb = 0; eb < 4; ++eb) o[eb][r] *= corr;
            Pl[wave][lg*4 + r][ln]      = f2bf(p0);
            Pl[wave][lg*4 + r][16 + ln] = f2bf(p1);
        }
        ushort8 praw = *(const ushort8*)&Pl[wave][ln][lg*8];
        short8  pa   = __builtin_bit_cast(short8, praw);
        #pragma unroll
        for (int eb = 0; eb < 4; ++eb) {
            ushort8 vraw = *(const ushort8*)&Vt[eb*16 + ln][lg*8];
            o[eb] = __builtin_amdgcn_mfma_f32_16x16x32_bf16(
                pa, __builtin_bit_cast(short8, vraw), o[eb], 0, 0, 0);
        }
    }

    float* Og = O + (size_t)bh * Lq * Ed;
    #pragma unroll
    for (int r = 0; r < 4; ++r) {
        float inv = 1.0f / sum[r];
        int row = q0 + lg * 4 + r;
        #pragma unroll
        for (int eb = 0; eb < 4; ++eb)
            Og[(size_t)row * Ed + eb*16 + ln] = o[eb][r] * inv;
    }
}

extern "C" void kernel_launch(void* const* d_in, const int* in_sizes, int n_in,
                              void* d_out, int out_size, void* d_ws, size_t ws_size,
                              hipStream_t stream) {
    const float* Q  = (const float*)d_in[0];
    const float* K  = (const float*)d_in[1];
    const float* V  = (const float*)d_in[2];
    const float* TD = (const float*)d_in[3];
    float* O = (float*)d_out;

    const size_t elems = (size_t)NBH * Sk * Ed;
    const size_t need  = 2 * elems * sizeof(unsigned short);   // 16 MB

    if (ws_size >= need) {
        unsigned short* Kb = (unsigned short*)d_ws;
        unsigned short* Vt = Kb + elems;
        prep_kv<<<dim3(3072), dim3(256), 0, stream>>>(K, V, Kb, Vt);
        ta_attn12<<<dim3(NBH * (Lq / QBLK)), dim3(512), 0, stream>>>(Q, TD, Kb, Vt, O);
    } else {
        ta_attn_fb<<<dim3(NBH * 16), dim3(256), 0, stream>>>(Q, K, V, TD, O);
    }
}

// Round 13
// 42.116 us; speedup vs baseline: 1.1178x; 1.1178x over previous
//
#include <hip/hip_runtime.h>
#include <hip/hip_bf16.h>

// TimeAwareFullAttention: O = softmax(SCALE * decay(b,l) * Q K^T) V
// B=8 H=8 L=S=1024 E=64, f32 in/out. decay = exp(-td/5), SCALE = 1/sqrt(5).
// FINAL (= round 10, best verified: 42.2us total, absmax 0.047).
// Lever ledger: r11 carried-pa pipeline -> miscompile-pattern FAIL;
// r12 V-to-registers overlap -> -5us regression (compiler schedule +VGPR).
// Structure: fused pre-pass converts K (swizzled bf16) and V (transposed
// swizzled bf16) into d_ws once; main kernel = 512-thread blocks, two
// 4-wave KV-split half-groups each streaming 8 kv tiles with their own
// K/V LDS double-buffer (64 KB), staged via global_load_lds(16B);
// 32x32x16 bf16 MFMA with swapped QK^T (S^T = mfma(K,Q)) so softmax rows
// are lane-local; P stays in-register via v_cvt_pk_bf16_f32 +
// v_permlane32_swap_b32 (linear kv order); fixed-m softmax (m=0, shift
// invariance: scores*log2e within ~+-35, far inside f32 range; bf16 P
// keeps relative precision) with raw v_exp_f32; XCD-aware block swizzle;
// end combine of the two halves through the dead K/V LDS.

#define Lq   1024
#define Sk   1024
#define Ed   64
#define QBLK 128
#define KVBLK 64
#define NTH  8             // kv tiles per half-group
#define NBH  64            // B*H

typedef __attribute__((ext_vector_type(8)))  short          short8;
typedef __attribute__((ext_vector_type(8)))  unsigned short ushort8;
typedef __attribute__((ext_vector_type(4)))  float          f32x4;
typedef __attribute__((ext_vector_type(16))) float          f32x16;
typedef __attribute__((ext_vector_type(4)))  unsigned int   uint4v;

__device__ __forceinline__ unsigned short f2bf(float x) {
    unsigned int u = __float_as_uint(x);
    u += 0x7FFFu + ((u >> 16) & 1u);   // round-to-nearest-even
    return (unsigned short)(u >> 16);
}

__device__ __forceinline__ unsigned cvt_pk_bf16(float lo, float hi) {
    unsigned r;
    asm("v_cvt_pk_bf16_f32 %0, %1, %2" : "=v"(r) : "v"(lo), "v"(hi));
    return r;
}

__device__ __forceinline__ void gl_lds16(const void* g, void* lds) {
    __builtin_amdgcn_global_load_lds(
        (const __attribute__((address_space(1))) void*)g,
        (__attribute__((address_space(3))) void*)lds, 16, 0, 0);
}

// ---- fused pre-pass ----
// K: bf16, 16B-block swizzled: Kb[row][ (jb ^ (row&7))*8 + i ] = K[row][jb*8+i]
// V: bf16 transposed per (b,h), swizzled within each 64-kv group:
//    Vt[bh][e][kv0 + (jb ^ (e&7))*8 + i] = V[bh][kv0 + jb*8 + i][e]
__global__ __launch_bounds__(256) void prep_kv(const float* __restrict__ K,
                                               const float* __restrict__ V,
                                               unsigned short* __restrict__ Kb,
                                               unsigned short* __restrict__ Vt) {
    int bid = blockIdx.x;
    if (bid < 2048) {
        int gid = bid * 256 + threadIdx.x;   // over (B*H*S)*8
        int row = gid >> 3;
        int jb  = gid & 7;
        const float* src = K + (size_t)row * Ed + jb * 8;
        float4 a = *(const float4*)src;
        float4 c = *(const float4*)(src + 4);
        ushort8 w;
        w[0]=f2bf(a.x); w[1]=f2bf(a.y); w[2]=f2bf(a.z); w[3]=f2bf(a.w);
        w[4]=f2bf(c.x); w[5]=f2bf(c.y); w[6]=f2bf(c.z); w[7]=f2bf(c.w);
        *(ushort8*)(Kb + (size_t)row * Ed + ((jb ^ (row & 7)) << 3)) = w;
    } else {
        int vb  = bid - 2048;
        int bh  = vb >> 4;
        int kv0 = (vb & 15) * KVBLK;
        int e   = threadIdx.x & 63;
        int jh  = threadIdx.x >> 6;
        const float* Vg = V + (size_t)bh * Sk * Ed;
        unsigned short* Vo = Vt + (size_t)bh * Ed * Sk;
        #pragma unroll
        for (int half = 0; half < 2; ++half) {
            int jb = jh + half * 4;
            ushort8 w;
            #pragma unroll
            for (int i = 0; i < 8; ++i)
                w[i] = f2bf(Vg[(size_t)(kv0 + jb * 8 + i) * Ed + e]);  // coalesced over e
            *(ushort8*)(Vo + (size_t)e * Sk + kv0 + ((jb ^ (e & 7)) << 3)) = w;
        }
    }
}

// ------------------------------- main kernel --------------------------------
__global__ __launch_bounds__(512, 4) void ta_attn10(
    const float* __restrict__ Q, const float* __restrict__ TD,
    const unsigned short* __restrict__ Kb, const unsigned short* __restrict__ Vt,
    float* __restrict__ O)
{
    // [half][ K dbuf 2x8KB | V dbuf 2x8KB ] = 64 KB; reused for the combine.
    __shared__ __align__(16) char smem[65536];

    // T1: 512 wgs -> XCD d%8 owns 64 contiguous wgs = 8 (b,h) x 8 q-blocks
    const int d    = blockIdx.x;
    const int wg   = (d & 7) * 64 + (d >> 3);
    const int bh   = wg >> 3;
    const int qb   = wg & 7;
    const int b    = bh >> 3;
    const int tid  = threadIdx.x;
    const int wave = tid >> 6, lane = tid & 63;
    const int half = wave >> 2, qw = wave & 3;
    const int ln31 = lane & 31;
    const int hi   = lane >> 5;
    const int l7   = ln31 & 7;
    const int st   = tid & 255;          // staging index within the half-group

    const char* KbBH = (const char*)(Kb + (size_t)bh * Sk * Ed);
    const char* VtBH = (const char*)(Vt + (size_t)bh * Ed * Sk);
    const int q0w = qb * QBLK + qw * 32;

    char* baseK = smem + half * 32768;
    char* baseV = baseK + 16384;

    // ---- stage this half's tile 0 ----
    {
        const size_t tg = (size_t)(half * NTH);
        #pragma unroll
        for (int p = 0; p < 2; ++p) {
            unsigned o_ = st * 16 + p * 4096;
            gl_lds16(KbBH + tg * 8192 + o_, baseK + o_);
            unsigned e = o_ >> 7, c = o_ & 127;
            gl_lds16(VtBH + (size_t)e * 2048 + tg * 128 + c, baseV + o_);
        }
    }

    // ---- Q fragments (B operand): col=q=ln31, k = kc*16 + hi*8 + j ----
    const float SCALE = 0.44721359549995793f;
    const float LOG2E = 1.4426950408889634f;
    const float rscale = SCALE * LOG2E * __expf(-TD[b * Lq + q0w + ln31] * 0.2f);
    short8 qa[4];
    {
        const float* qp = Q + ((size_t)bh * Lq + q0w + ln31) * Ed + hi * 8;
        #pragma unroll
        for (int kc = 0; kc < 4; ++kc) {
            float4 a = *(const float4*)(qp + kc * 16);
            float4 c = *(const float4*)(qp + kc * 16 + 4);
            ushort8 t;
            t[0]=f2bf(a.x*rscale); t[1]=f2bf(a.y*rscale);
            t[2]=f2bf(a.z*rscale); t[3]=f2bf(a.w*rscale);
            t[4]=f2bf(c.x*rscale); t[5]=f2bf(c.y*rscale);
            t[6]=f2bf(c.z*rscale); t[7]=f2bf(c.w*rscale);
            qa[kc] = __builtin_bit_cast(short8, t);
        }
    }

    float sum = 0.f;                 // in-lane partial denominator for q=ln31
    f32x16 o[2];
    #pragma unroll
    for (int eb = 0; eb < 2; ++eb)
        #pragma unroll
        for (int i = 0; i < 16; ++i) o[eb][i] = 0.f;

    int cur = 0;
    for (int tt = 0; tt < NTH; ++tt) {
        __syncthreads();   // tile staged (vmcnt drained); prev reads done
        if (tt + 1 < NTH) {
            const size_t tg = (size_t)(half * NTH + tt + 1);
            char* kd = baseK + (cur ^ 1) * 8192;
            char* vd = baseV + (cur ^ 1) * 8192;
            #pragma unroll
            for (int p = 0; p < 2; ++p) {
                unsigned o_ = st * 16 + p * 4096;
                gl_lds16(KbBH + tg * 8192 + o_, kd + o_);
                unsigned e = o_ >> 7, c = o_ & 127;
                gl_lds16(VtBH + (size_t)e * 2048 + tg * 128 + c, vd + o_);
            }
        }
        const char* kb = baseK + cur * 8192;
        const char* vb = baseV + cur * 8192;

        // ---- S^T = K Q^T : D[kv 32 per kvb][q=ln31], A=K rows, B=Q ----
        f32x16 s[2];
        __builtin_amdgcn_s_setprio(1);
        #pragma unroll
        for (int kvb = 0; kvb < 2; ++kvb) {
            #pragma unroll
            for (int i = 0; i < 16; ++i) s[kvb][i] = 0.f;
            #pragma unroll
            for (int kc = 0; kc < 4; ++kc) {
                ushort8 kr = *(const ushort8*)(kb
                    + (kvb * 32 + ln31) * 128 + (((2 * kc + hi) ^ l7) << 4));
                s[kvb] = __builtin_amdgcn_mfma_f32_32x32x16_bf16(
                    __builtin_bit_cast(short8, kr), qa[kc], s[kvb], 0, 0, 0);
            }
        }
        __builtin_amdgcn_s_setprio(0);

        // ---- P = 2^s via raw v_exp_f32 (scores within +-~35, no denorm
        // handling needed); in-lane sum; pack pairs w[kvb][m'][h] ----
        unsigned w[2][4][2];
        #pragma unroll
        for (int kvb = 0; kvb < 2; ++kvb)
            #pragma unroll
            for (int mp = 0; mp < 4; ++mp) {
                float p0 = __builtin_amdgcn_exp2f(s[kvb][4 * mp + 0]);
                float p1 = __builtin_amdgcn_exp2f(s[kvb][4 * mp + 1]);
                float p2 = __builtin_amdgcn_exp2f(s[kvb][4 * mp + 2]);
                float p3 = __builtin_amdgcn_exp2f(s[kvb][4 * mp + 3]);
                sum += (p0 + p1) + (p2 + p3);
                w[kvb][mp][0] = cvt_pk_bf16(p0, p1);
                w[kvb][mp][1] = cvt_pk_bf16(p2, p3);
            }

        // ---- permlane32_swap -> pa[ks] in LINEAR kv order ----
        short8 pa[4];
        #pragma unroll
        for (int ks = 0; ks < 4; ++ks) {
            const int kvb = ks >> 1, mm = ks & 1;
            unsigned a0 = w[kvb][2 * mm][0], b0 = w[kvb][2 * mm + 1][0];
            unsigned a1 = w[kvb][2 * mm][1], b1 = w[kvb][2 * mm + 1][1];
            asm volatile("v_permlane32_swap_b32 %0, %1" : "+v"(a0), "+v"(b0));
            asm volatile("v_permlane32_swap_b32 %0, %1" : "+v"(a1), "+v"(b1));
            uint4v u; u[0] = a0; u[1] = a1; u[2] = b0; u[3] = b1;
            pa[ks] = __builtin_bit_cast(short8, u);
        }

        // ---- O += P V : A=pa (row=q=ln31), B=V[kv][e per eb] ----
        __builtin_amdgcn_s_setprio(1);
        #pragma unroll
        for (int eb = 0; eb < 2; ++eb)
            #pragma unroll
            for (int ks = 0; ks < 4; ++ks) {
                ushort8 vr = *(const ushort8*)(vb
                    + (eb * 32 + ln31) * 128 + (((2 * ks + hi) ^ l7) << 4));
                o[eb] = __builtin_amdgcn_mfma_f32_32x32x16_bf16(
                    pa[ks], __builtin_bit_cast(short8, vr), o[eb], 0, 0, 0);
            }
        __builtin_amdgcn_s_setprio(0);
        cur ^= 1;
    }

    // ---- combine halves through LDS (K/V buffers are dead now) ----
    __syncthreads();
    float* Lo = (float*)smem;              // 32 KB: [qw][eb*4+c4][lane] f32x4
    float* Ls = (float*)(smem + 32768);    // 1 KB:  [qw][lane]
    if (half == 1) {
        Ls[qw * 64 + lane] = sum + __shfl_xor(sum, 32);
        #pragma unroll
        for (int eb = 0; eb < 2; ++eb)
            #pragma unroll
            for (int c4 = 0; c4 < 4; ++c4) {
                f32x4 v = { o[eb][c4*4+0], o[eb][c4*4+1],
                            o[eb][c4*4+2], o[eb][c4*4+3] };
                *(f32x4*)(Lo + qw * 2048 + (eb * 4 + c4) * 256 + lane * 4) = v;
            }
    }
    __syncthreads();
    if (half == 0) {
        float stot = sum + __shfl_xor(sum, 32) + Ls[qw * 64 + lane];
        #pragma unroll
        for (int eb = 0; eb < 2; ++eb)
            #pragma unroll
            for (int c4 = 0; c4 < 4; ++c4) {
                f32x4 v = *(const f32x4*)(Lo + qw * 2048 + (eb * 4 + c4) * 256 + lane * 4);
                o[eb][c4*4+0] += v[0]; o[eb][c4*4+1] += v[1];
                o[eb][c4*4+2] += v[2]; o[eb][c4*4+3] += v[3];
            }
        float* Og = O + (size_t)bh * Lq * Ed;
        #pragma unroll
        for (int r = 0; r < 16; ++r) {
            const int qrow = (r & 3) + 8 * (r >> 2) + 4 * hi;
            float inv = 1.0f / __shfl(stot, qrow);
            float* op = Og + (size_t)(q0w + qrow) * Ed + ln31;
            op[0]  = o[0][r] * inv;
            op[32] = o[1][r] * inv;
        }
    }
}

// ------------------- round-1 fallback (ws too small) ------------------------
__global__ __launch_bounds__(256, 2) void ta_attn_fb(
    const float* __restrict__ Q, const float* __restrict__ K,
    const float* __restrict__ V, const float* __restrict__ TD,
    float* __restrict__ O)
{
    __shared__ __align__(16) unsigned short Kl[32][72];
    __shared__ __align__(16) unsigned short Vt[Ed][40];
    __shared__ __align__(16) unsigned short Pl[4][16][40];

    const int bid  = blockIdx.x;
    const int bh   = bid >> 4;
    const int qb   = bid & 15;
    const int b    = bh >> 3;
    const int tid  = threadIdx.x;
    const int wave = tid >> 6, lane = tid & 63;
    const int lg   = lane >> 4;
    const int ln   = lane & 15;

    const float* Qg = Q + (size_t)bh * Lq * Ed;
    const float* Kg = K + (size_t)bh * Sk * Ed;
    const float* Vg = V + (size_t)bh * Sk * Ed;
    const int q0 = qb * 64 + wave * 16;

    short8 qa[2];
    {
        const float* qp = Qg + (size_t)(q0 + ln) * Ed + lg * 8;
        for (int ks = 0; ks < 2; ++ks) {
            float4 a = *(const float4*)(qp + ks * 32);
            float4 c = *(const float4*)(qp + ks * 32 + 4);
            ushort8 t2;
            t2[0]=f2bf(a.x); t2[1]=f2bf(a.y); t2[2]=f2bf(a.z); t2[3]=f2bf(a.w);
            t2[4]=f2bf(c.x); t2[5]=f2bf(c.y); t2[6]=f2bf(c.z); t2[7]=f2bf(c.w);
            qa[ks] = __builtin_bit_cast(short8, t2);
        }
    }

    const float SCALE = 0.44721359549995793f;
    float rs[4], m[4], sum[4];
    for (int r = 0; r < 4; ++r) {
        int row = q0 + lg * 4 + r;
        rs[r]  = SCALE * __expf(-TD[b * Lq + row] * 0.2f);
        m[r]   = -1e30f;
        sum[r] = 0.f;
    }
    f32x4 o[4];
    for (int eb = 0; eb < 4; ++eb) o[eb] = (f32x4){0.f, 0.f, 0.f, 0.f};

    const int srow = tid >> 3;
    const int scol = (tid & 7) * 8;

    for (int t = 0; t < 32; ++t) {
        const int kv0 = t * 32;
        __syncthreads();
        {
            const float* kp = Kg + (size_t)(kv0 + srow) * Ed + scol;
            float4 a = *(const float4*)kp;
            float4 c = *(const float4*)(kp + 4);
            ushort8 tk;
            tk[0]=f2bf(a.x); tk[1]=f2bf(a.y); tk[2]=f2bf(a.z); tk[3]=f2bf(a.w);
            tk[4]=f2bf(c.x); tk[5]=f2bf(c.y); tk[6]=f2bf(c.z); tk[7]=f2bf(c.w);
            *(ushort8*)&Kl[srow][scol] = tk;
            const float* vp = Vg + (size_t)(kv0 + srow) * Ed + scol;
            float4 va = *(const float4*)vp;
            float4 vc = *(const float4*)(vp + 4);
            float vv[8] = {va.x,va.y,va.z,va.w,vc.x,vc.y,vc.z,vc.w};
            #pragma unroll
            for (int i = 0; i < 8; ++i) Vt[scol + i][srow] = f2bf(vv[i]);
        }
        __syncthreads();

        f32x4 s[2];
        #pragma unroll
        for (int cb = 0; cb < 2; ++cb) {
            s[cb] = (f32x4){0.f, 0.f, 0.f, 0.f};
            #pragma unroll
            for (int ks = 0; ks < 2; ++ks) {
                ushort8 kraw = *(const ushort8*)&Kl[cb*16 + ln][lg*8 + ks*32];
                s[cb] = __builtin_amdgcn_mfma_f32_16x16x32_bf16(
                    qa[ks], __builtin_bit_cast(short8, kraw), s[cb], 0, 0, 0);
            }
        }
        #pragma unroll
        for (int r = 0; r < 4; ++r) {
            float s0 = s[0][r] * rs[r];
            float s1 = s[1][r] * rs[r];
            float tm = fmaxf(s0, s1);
            tm = fmaxf(tm, __shfl_xor(tm, 1));
            tm = fmaxf(tm, __shfl_xor(tm, 2));
            tm = fmaxf(tm, __shfl_xor(tm, 4));
            tm = fmaxf(tm, __shfl_xor(tm, 8));
            float mn   = fmaxf(m[r], tm);
            float corr = __expf(m[r] - mn);
            m[r] = mn;
            float p0 = __expf(s0 - mn);
            float p1 = __expf(s1 - mn);
            float ts = p0 + p1;
            ts += __shfl_xor(ts, 1);
            ts += __shfl_xor(ts, 2);
            ts += __shfl_xor(ts, 4);
            ts += __shfl_xor(ts, 8);
            sum[r] = sum[r] * corr + ts;
            #pragma unroll
            for (int eb = 0; eb < 4; ++eb) o[eb][r] *= corr;
            Pl[wave][lg*4 + r][ln]      = f2bf(p0);
            Pl[wave][lg*4 + r][16 + ln] = f2bf(p1);
        }
        ushort8 praw = *(const ushort8*)&Pl[wave][ln][lg*8];
        short8  pa   = __builtin_bit_cast(short8, praw);
        #pragma unroll
        for (int eb = 0; eb < 4; ++eb) {
            ushort8 vraw = *(const ushort8*)&Vt[eb*16 + ln][lg*8];
            o[eb] = __builtin_amdgcn_mfma_f32_16x16x32_bf16(
                pa, __builtin_bit_cast(short8, vraw), o[eb], 0, 0, 0);
        }
    }

    float* Og = O + (size_t)bh * Lq * Ed;
    #pragma unroll
    for (int r = 0; r < 4; ++r) {
        float inv = 1.0f / sum[r];
        int row = q0 + lg * 4 + r;
        #pragma unroll
        for (int eb = 0; eb < 4; ++eb)
            Og[(size_t)row * Ed + eb*16 + ln] = o[eb][r] * inv;
    }
}

extern "C" void kernel_launch(void* const* d_in, const int* in_sizes, int n_in,
                              void* d_out, int out_size, void* d_ws, size_t ws_size,
                              hipStream_t stream) {
    const float* Q  = (const float*)d_in[0];
    const float* K  = (const float*)d_in[1];
    const float* V  = (const float*)d_in[2];
    const float* TD = (const float*)d_in[3];
    float* O = (float*)d_out;

    const size_t elems = (size_t)NBH * Sk * Ed;
    const size_t need  = 2 * elems * sizeof(unsigned short);   // 16 MB

    if (ws_size >= need) {
        unsigned short* Kb = (unsigned short*)d_ws;
        unsigned short* Vt = Kb + elems;
        prep_kv<<<dim3(3072), dim3(256), 0, stream>>>(K, V, Kb, Vt);
        ta_attn10<<<dim3(NBH * (Lq / QBLK)), dim3(512), 0, stream>>>(Q, TD, Kb, Vt, O);
    } else {
        ta_attn_fb<<<dim3(NBH * 16), dim3(256), 0, stream>>>(Q, K, V, TD, O);
    }
}